// Round 7
// baseline (166.240 us; speedup 1.0000x reference)
//
#include <hip/hip_runtime.h>

// VQ nearest-codeword argmin. N=262144 rows (D=64 f32), K=512, out int32.
//
// R7: prep kernel (codebook -> bf16 pre-swizzled image + f32 norms in ws) ->
// main kernel: whole 64 KiB codebook DMA'd to LDS once, ONE barrier, then
// each wave independently handles 64 rows x 512 codewords:
//   sweep1: MFMA bf16 dots (8 MFMA per 2 LDS reads), fold fmax(dot)
//   reduce: 16-lane shfl fmax -> per-row max dot
//   thr = -2*dmax + CMAX + S*2^-15 + 1e-4      (validated R4/R5/R6 margin)
//   sweep2: recompute (bit-identical), site test core<=thr -> per-wave LDS
//           queue (atomicAdd push; noinline immediate-refine on overflow)
//   drain:  wave-cooperative refine of queued (row,k): exact f32, numpy
//           rounding contract (absmax=0 in R1/R2/R4/R5/R6):
//           dist = fl(fl(A - 2*dot) + C) contract-off; A = numpy 8-acc
//           pairwise. Tie: (dist_bits<<32)|k u64 atomicMin (wave-private).
// CMAX = 64*(1/512)^2 = 2.44140625e-4; min(core) <= -2*dmax + CMAX keeps
// the capture guarantee. |core_bf - core| <= S*2^-16 per side.
//
// All of bestS/ArowS/SrowS/queue are wave-private (rows wv*64..wv*64+63 are
// exactly threads wv*64..wv*64+63) -> single __syncthreads (cbBf+cnormS).

typedef __attribute__((ext_vector_type(8))) short bf16x8;
typedef __attribute__((ext_vector_type(4))) float f32x4;

constexpr int DCB = 64;
constexpr size_t WS_CB    = 0;        // 64 KiB bf16 pre-swizzled image
constexpr size_t WS_CNORM = 65536;    // f32[512]

static __device__ inline unsigned short f2bf(float f) {  // f32->bf16 RNE
  unsigned u = __float_as_uint(f);
  return (unsigned short)((u + 0x7FFFu + ((u >> 16) & 1u)) >> 16);
}

// swizzled byte offset in a [rows][64 bf16] image (128 B rows), XOR bits 4-6
#define SWZ(row, b) (((row) << 7) + ((b) ^ (((row) & 7) << 4)))

// ---------------- prep kernel: codebook image + norms ----------------
__global__ __launch_bounds__(256) void vq_prep_kernel(
    const float* __restrict__ cb, unsigned char* __restrict__ ws)
{
  const int k = blockIdx.x * 256 + threadIdx.x;   // 0..511
  const float4* e4 = reinterpret_cast<const float4*>(cb + (size_t)k * DCB);
  float4 e[16];
  #pragma unroll
  for (int j = 0; j < 16; ++j) e[j] = e4[j];
  float s0 = 0.f, s1 = 0.f, s2 = 0.f, s3 = 0.f;
  #pragma unroll
  for (int j = 0; j < 16; ++j) {
    s0 = fmaf(e[j].x, e[j].x, s0); s1 = fmaf(e[j].y, e[j].y, s1);
    s2 = fmaf(e[j].z, e[j].z, s2); s3 = fmaf(e[j].w, e[j].w, s3);
  }
  ((float*)(ws + WS_CNORM))[k] = (s0 + s1) + (s2 + s3);

  const int r = k & 255;
  unsigned char* img = ws + WS_CB + (size_t)(k >> 8) * 32768 + (size_t)r * 128;
  #pragma unroll
  for (int c16 = 0; c16 < 8; ++c16) {      // 16B chunk -> pre-swizzled slot
    uint4 w;
    w.x = (unsigned)f2bf(e[2*c16].x)   | ((unsigned)f2bf(e[2*c16].y)   << 16);
    w.y = (unsigned)f2bf(e[2*c16].z)   | ((unsigned)f2bf(e[2*c16].w)   << 16);
    w.z = (unsigned)f2bf(e[2*c16+1].x) | ((unsigned)f2bf(e[2*c16+1].y) << 16);
    w.w = (unsigned)f2bf(e[2*c16+1].z) | ((unsigned)f2bf(e[2*c16+1].w) << 16);
    *reinterpret_cast<uint4*>(img + ((c16 ^ (r & 7)) << 4)) = w;
  }
}

// ---------------- main kernel ----------------
static __device__ __attribute__((noinline)) void refine_rk(
    int row0, int row_local, int k,
    const float* __restrict__ z, const float* __restrict__ cb,
    const float* ArowSp, const float* cnormSp, unsigned long long* bestSp)
{
  const float* zr = z + (size_t)(row0 + row_local) * DCB;
  const float* e  = cb + (size_t)k * DCB;
  float d0 = 0.f, d1 = 0.f, d2 = 0.f, d3 = 0.f;
  #pragma unroll
  for (int j = 0; j < DCB; j += 4) {
    d0 = fmaf(zr[j + 0], e[j + 0], d0);
    d1 = fmaf(zr[j + 1], e[j + 1], d1);
    d2 = fmaf(zr[j + 2], e[j + 2], d2);
    d3 = fmaf(zr[j + 3], e[j + 3], d3);
  }
  const float dot = (d0 + d1) + (d2 + d3);
  const float A  = ArowSp[row_local];
  const float Ck = cnormSp[k];
  float dist;
  {
    #pragma clang fp contract(off)
    dist = (A - 2.0f * dot) + Ck;   // two separately-rounded f32 ops
  }
  unsigned long long packed =
      ((unsigned long long)__float_as_uint(dist) << 32) | (unsigned)k;
  atomicMin(bestSp + row_local, packed);
}

static __device__ inline bf16x8 pack8(float4 a, float4 b) {
  bf16x8 r;
  r[0] = (short)f2bf(a.x); r[1] = (short)f2bf(a.y);
  r[2] = (short)f2bf(a.z); r[3] = (short)f2bf(a.w);
  r[4] = (short)f2bf(b.x); r[5] = (short)f2bf(b.y);
  r[6] = (short)f2bf(b.z); r[7] = (short)f2bf(b.w);
  return r;
}

__global__ __launch_bounds__(512, 4) void vq_main_kernel(
    const float* __restrict__ z, const float* __restrict__ cb,
    const unsigned char* __restrict__ ws, int* __restrict__ out, int N)
{
  __shared__ unsigned short cbBf[512 * DCB];    // 64 KiB whole codebook (swz)
  __shared__ float cnormS[512];                 // 2 KiB
  __shared__ float ArowS[512];                  // 2 KiB exact pairwise ||z||^2
  __shared__ float SrowS[512];                  // 2 KiB sum|z|
  __shared__ unsigned long long bestS[512];     // 4 KiB packed (dist,k)
  __shared__ unsigned qCnt[8];                  // per-wave candidate count
  __shared__ unsigned qBuf[8][128];             // per-wave candidate queue 4 KiB
  // total LDS = 79,904 B -> 2 blocks/CU

  const int tid = threadIdx.x;
  const int lane = tid & 63, wv = tid >> 6;
  const int g = lane >> 4, lm = lane & 15;
  const int row0 = blockIdx.x * 512;

  // ---- Phase 0 (single barrier at the end) ----
  // (a) DMA whole codebook image: 64 slabs of 1 KiB, 8 per wave
  {
    const unsigned char* src = ws + WS_CB;
    #pragma unroll
    for (int q = 0; q < 8; ++q) {
      const int slab = wv * 8 + q;
      const unsigned char* gp = src + slab * 1024 + lane * 16;
      char* lp = (char*)cbBf + slab * 1024;  // wave-uniform; HW adds lane*16
      __builtin_amdgcn_global_load_lds(
          (const __attribute__((address_space(1))) unsigned int*)gp,
          (__attribute__((address_space(3))) unsigned int*)lp, 16, 0, 0);
    }
  }
  // (b) cnorm -> LDS; init wave-private bestS / qCnt
  cnormS[tid] = ((const float*)(ws + WS_CNORM))[tid];
  bestS[tid] = ~0ull;            // tid == own wave's row range
  if (lane == 0) qCnt[wv] = 0u;
  // (c) exact pairwise A (numpy 8-acc) + S = sum|z|; one row per thread
  {
    const float4* q4 = reinterpret_cast<const float4*>(z + (size_t)(row0 + tid) * DCB);
    float4 q[16];
    #pragma unroll
    for (int j = 0; j < 16; ++j) q[j] = q4[j];
    float A;
    {
      #pragma clang fp contract(off)
      float r0 = q[0].x*q[0].x, r1 = q[0].y*q[0].y, r2 = q[0].z*q[0].z, r3 = q[0].w*q[0].w;
      float r4 = q[1].x*q[1].x, r5 = q[1].y*q[1].y, r6 = q[1].z*q[1].z, r7 = q[1].w*q[1].w;
      #pragma unroll
      for (int a = 1; a < 8; ++a) {
        r0 += q[2*a].x*q[2*a].x;     r1 += q[2*a].y*q[2*a].y;
        r2 += q[2*a].z*q[2*a].z;     r3 += q[2*a].w*q[2*a].w;
        r4 += q[2*a+1].x*q[2*a+1].x; r5 += q[2*a+1].y*q[2*a+1].y;
        r6 += q[2*a+1].z*q[2*a+1].z; r7 += q[2*a+1].w*q[2*a+1].w;
      }
      A = ((r0 + r1) + (r2 + r3)) + ((r4 + r5) + (r6 + r7));
    }
    ArowS[tid] = A;
    float s0 = 0.f, s1 = 0.f, s2 = 0.f, s3 = 0.f;
    #pragma unroll
    for (int j = 0; j < 16; ++j) {
      s0 += fabsf(q[j].x); s1 += fabsf(q[j].y);
      s2 += fabsf(q[j].z); s3 += fabsf(q[j].w);
    }
    SrowS[tid] = (s0 + s1) + (s2 + s3);
  }
  // (d) A-fragments: 4 row-tiles x 2 k-steps, from global f32 (L2-hot)
  bf16x8 afr[4][2];
  #pragma unroll
  for (int rt = 0; rt < 4; ++rt) {
    const float* zrow = z + (size_t)(row0 + wv * 64 + rt * 16 + lm) * DCB;
    #pragma unroll
    for (int s = 0; s < 2; ++s) {
      const float4 u0 = *reinterpret_cast<const float4*>(zrow + 32 * s + 8 * g);
      const float4 u1 = *reinterpret_cast<const float4*>(zrow + 32 * s + 8 * g + 4);
      afr[rt][s] = pack8(u0, u1);
    }
  }
  __syncthreads();   // drains DMA (vmcnt) + LDS writes; the ONLY block barrier

  // ---- Sweep 1: fold max(dot) per (rt,i) ----
  float dmax[4][4];
  #pragma unroll
  for (int rt = 0; rt < 4; ++rt)
    #pragma unroll
    for (int i = 0; i < 4; ++i) dmax[rt][i] = -__builtin_inff();

  #pragma unroll 8
  for (int ct = 0; ct < 32; ++ct) {
    const int rowc = ct * 16 + lm;
    const bf16x8 b0 = *reinterpret_cast<const bf16x8*>((const char*)cbBf + SWZ(rowc, 16 * g));
    const bf16x8 b1 = *reinterpret_cast<const bf16x8*>((const char*)cbBf + SWZ(rowc, 16 * g + 64));
    f32x4 a0 = (f32x4)0.0f, a1 = (f32x4)0.0f, a2 = (f32x4)0.0f, a3 = (f32x4)0.0f;
    a0 = __builtin_amdgcn_mfma_f32_16x16x32_bf16(afr[0][0], b0, a0, 0, 0, 0);
    a0 = __builtin_amdgcn_mfma_f32_16x16x32_bf16(afr[0][1], b1, a0, 0, 0, 0);
    a1 = __builtin_amdgcn_mfma_f32_16x16x32_bf16(afr[1][0], b0, a1, 0, 0, 0);
    a1 = __builtin_amdgcn_mfma_f32_16x16x32_bf16(afr[1][1], b1, a1, 0, 0, 0);
    a2 = __builtin_amdgcn_mfma_f32_16x16x32_bf16(afr[2][0], b0, a2, 0, 0, 0);
    a2 = __builtin_amdgcn_mfma_f32_16x16x32_bf16(afr[2][1], b1, a2, 0, 0, 0);
    a3 = __builtin_amdgcn_mfma_f32_16x16x32_bf16(afr[3][0], b0, a3, 0, 0, 0);
    a3 = __builtin_amdgcn_mfma_f32_16x16x32_bf16(afr[3][1], b1, a3, 0, 0, 0);
    #pragma unroll
    for (int i = 0; i < 4; ++i) {
      dmax[0][i] = fmaxf(dmax[0][i], a0[i]);
      dmax[1][i] = fmaxf(dmax[1][i], a1[i]);
      dmax[2][i] = fmaxf(dmax[2][i], a2[i]);
      dmax[3][i] = fmaxf(dmax[3][i], a3[i]);
    }
  }

  // ---- per-row max dot across the 16-lane (lm) group ----
  #pragma unroll
  for (int mask = 1; mask <= 8; mask <<= 1)
    #pragma unroll
    for (int rt = 0; rt < 4; ++rt)
      #pragma unroll
      for (int i = 0; i < 4; ++i)
        dmax[rt][i] = fmaxf(dmax[rt][i], __shfl_xor(dmax[rt][i], mask));

  // ---- thresholds: -2*dmax + CMAX + S*2^-15 + 1e-4 ----
  float thr[4][4];
  #pragma unroll
  for (int rt = 0; rt < 4; ++rt) {
    const float4 Sv = *reinterpret_cast<const float4*>(&SrowS[wv * 64 + rt * 16 + g * 4]);
    const float s4[4] = {Sv.x, Sv.y, Sv.z, Sv.w};
    #pragma unroll
    for (int i = 0; i < 4; ++i)
      thr[rt][i] = fmaf(-2.0f, dmax[rt][i],
                        fmaf(s4[i], 3.0517578125e-5f, 3.44140625e-4f));
  }

  // ---- Sweep 2: recompute (bit-identical), push candidates to wave queue --
  #pragma unroll 8
  for (int ct = 0; ct < 32; ++ct) {
    const int rowc = ct * 16 + lm;
    const bf16x8 b0 = *reinterpret_cast<const bf16x8*>((const char*)cbBf + SWZ(rowc, 16 * g));
    const bf16x8 b1 = *reinterpret_cast<const bf16x8*>((const char*)cbBf + SWZ(rowc, 16 * g + 64));
    f32x4 a0 = (f32x4)0.0f, a1 = (f32x4)0.0f, a2 = (f32x4)0.0f, a3 = (f32x4)0.0f;
    a0 = __builtin_amdgcn_mfma_f32_16x16x32_bf16(afr[0][0], b0, a0, 0, 0, 0);
    a0 = __builtin_amdgcn_mfma_f32_16x16x32_bf16(afr[0][1], b1, a0, 0, 0, 0);
    a1 = __builtin_amdgcn_mfma_f32_16x16x32_bf16(afr[1][0], b0, a1, 0, 0, 0);
    a1 = __builtin_amdgcn_mfma_f32_16x16x32_bf16(afr[1][1], b1, a1, 0, 0, 0);
    a2 = __builtin_amdgcn_mfma_f32_16x16x32_bf16(afr[2][0], b0, a2, 0, 0, 0);
    a2 = __builtin_amdgcn_mfma_f32_16x16x32_bf16(afr[2][1], b1, a2, 0, 0, 0);
    a3 = __builtin_amdgcn_mfma_f32_16x16x32_bf16(afr[3][0], b0, a3, 0, 0, 0);
    a3 = __builtin_amdgcn_mfma_f32_16x16x32_bf16(afr[3][1], b1, a3, 0, 0, 0);
    const float Cc = cnormS[rowc];
    #pragma unroll
    for (int rt = 0; rt < 4; ++rt) {
      #pragma unroll
      for (int i = 0; i < 4; ++i) {
        const float av = (rt == 0) ? a0[i] : (rt == 1) ? a1[i]
                       : (rt == 2) ? a2[i] : a3[i];
        const float core = fmaf(-2.0f, av, Cc);
        if (core <= thr[rt][i]) {           // rare (~0.3% of sites)
          const unsigned rec = (unsigned)ct | ((unsigned)rt << 5) |
                               ((unsigned)i << 7) | ((unsigned)g << 9) |
                               ((unsigned)lm << 11);
          const unsigned slot = atomicAdd(&qCnt[wv], 1u);
          if (slot < 128u) qBuf[wv][slot] = rec;
          else refine_rk(row0, wv * 64 + rt * 16 + g * 4 + i, ct * 16 + lm,
                         z, cb, ArowS, cnormS, bestS);
        }
      }
    }
  }

  // ---- drain wave queue: refines distributed evenly over 64 lanes ----
  {
    unsigned cnt = qCnt[wv];
    cnt = cnt < 128u ? cnt : 128u;
    for (unsigned idx = (unsigned)lane; idx < cnt; idx += 64u) {
      const unsigned rec = qBuf[wv][idx];
      const int ct2 = (int)(rec & 31u), rt2 = (int)((rec >> 5) & 3u);
      const int i2 = (int)((rec >> 7) & 3u), g2 = (int)((rec >> 9) & 3u);
      const int lm2 = (int)((rec >> 11) & 15u);
      refine_rk(row0, wv * 64 + rt2 * 16 + g2 * 4 + i2, ct2 * 16 + lm2,
                z, cb, ArowS, cnormS, bestS);
    }
  }

  // ---- write indices (tid's row is wave-private; same-wave LDS ordered) --
  out[row0 + tid] = (int)(bestS[tid] & 0xFFFFFFFFull);
}

extern "C" void kernel_launch(void* const* d_in, const int* in_sizes, int n_in,
                              void* d_out, int out_size, void* d_ws, size_t ws_size,
                              hipStream_t stream) {
  const float* z  = (const float*)d_in[0];   // [N, 64] f32
  const float* cb = (const float*)d_in[1];   // [512, 64] f32
  int* out = (int*)d_out;                    // [N] int32 indices
  unsigned char* ws = (unsigned char*)d_ws;  // needs ~68 KiB

  const int N = in_sizes[0] / DCB;           // 262144

  vq_prep_kernel<<<2, 256, 0, stream>>>(cb, ws);
  vq_main_kernel<<<N / 512, 512, 0, stream>>>(z, cb, ws, out, N);
}